// Round 1
// baseline (111.387 us; speedup 1.0000x reference)
//
#include <hip/hip_runtime.h>

#define NQ 14
#define DIM 16384
#define OUT_N 1000

__host__ __device__ constexpr int WI(int l, int i, int k) {
    return 14 + (l * 13 + i) * 2 + k;  // weights[l,i,k] angle slot (after 14 bias slots)
}

// Precompute cos(th/2), sin(th/2) for the 66 gate angles into d_ws.
__global__ void cs_kernel(const float* __restrict__ w,
                          const float* __restrict__ b,
                          float2* __restrict__ cs) {
    int g = threadIdx.x;
    if (g < 66) {
        float th = (g < NQ) ? b[g] : w[g - NQ];
        cs[g] = make_float2(cosf(0.5f * th), sinf(0.5f * th));
    }
}

// XOR-swizzle low 5 bits so all 6 exchange patterns are <=2-way bank aliased (free).
__device__ __forceinline__ int swz(int e) {
    return e ^ (((e >> 6) & 31) ^ (((e >> 11) & 1) << 4));
}

// RY on local bit B of a 64-element register tile: x0' = c x0 - s x1 ; x1' = s x0 + c x1
template<int B>
__device__ __forceinline__ void ry(float* x, float c, float s) {
#pragma unroll
    for (int m = 0; m < 32; ++m) {
        int l0 = ((m >> B) << (B + 1)) | (m & ((1 << B) - 1));
        int l1 = l0 | (1 << B);
        float x0 = x[l0], x1 = x[l1];
        x[l0] = c * x0 - s * x1;
        x[l1] = s * x0 + c * x1;
    }
}

// CZ: negate elements with both local bits set
template<int BH, int BL>
__device__ __forceinline__ void cz(float* x) {
#pragma unroll
    for (int l = 0; l < 64; ++l)
        if (((l >> BH) & 1) && ((l >> BL) & 1)) x[l] = -x[l];
}

// One entangling block B(l,i): CZ(i,i+1); RY(W[l,i,0]) on qubit i (local bit BH);
// RY(W[l,i,1]) on qubit i+1 (local bit BH-1).
#define BLOCK(BH, I0, I1)                                        \
    cz<BH, BH - 1>(x);                                           \
    { float2 c0 = csv[I0]; ry<BH>(x, c0.x, c0.y); }              \
    { float2 c1 = csv[I1]; ry<BH - 1>(x, c1.x, c1.y); }

// Window schedule (verified against the per-qubit dependency DAG):
//  S1 qubits 0-5  (index bits 13..8): init q0-5; B(0,0) B(0,2) B(0,4) B(0,1) B(0,3) B(1,0) B(1,2) B(1,1)
//  S2 qubits 6-11 (bits 7..2):        init q6-11; B(0,6) B(0,8) B(0,10) B(0,7) B(0,9) B(1,8)
//  S3 qubits 8-13 (bits 5..0):        init q12-13; B(0,12) B(0,11) B(1,10) B(1,12) B(1,9) B(1,11)
//  S4 qubits 3-8  (bits 10..5):       B(0,5) B(1,4) B(1,6) B(1,3) B(1,5) B(1,7)
__global__ __launch_bounds__(256, 2)
void qnn_kernel(const float* __restrict__ in,
                const float2* __restrict__ csv,
                float* __restrict__ out) {
    __shared__ float lds[DIM];          // exactly 64 KB; [0..3] reused as reduce scratch
    const int t = threadIdx.x;
    const int b = blockIdx.x;
    const float* __restrict__ xin = in + (size_t)b * DIM;

    // S1 layout: e = (l<<8) | t  -> lane-consecutive, coalesced
    float x[64];
#pragma unroll
    for (int l = 0; l < 64; ++l) x[l] = xin[(l << 8) | t];

    // sum of squares (norm folded into the final output scale; U is orthogonal)
    float p = 0.f;
#pragma unroll
    for (int l = 0; l < 64; ++l) p = fmaf(x[l], x[l], p);
#pragma unroll
    for (int d = 32; d; d >>= 1) p += __shfl_xor(p, d);
    if ((t & 63) == 0) lds[t >> 6] = p;
    __syncthreads();
    const float inv = 1.0f / (lds[0] + lds[1] + lds[2] + lds[3]);
    __syncthreads();   // all reads of lds[0..3] done before state writes below

    // ---- S1: qubit w -> local bit 5-w
    { float2 cc;
      cc = csv[0]; ry<5>(x, cc.x, cc.y);
      cc = csv[1]; ry<4>(x, cc.x, cc.y);
      cc = csv[2]; ry<3>(x, cc.x, cc.y);
      cc = csv[3]; ry<2>(x, cc.x, cc.y);
      cc = csv[4]; ry<1>(x, cc.x, cc.y);
      cc = csv[5]; ry<0>(x, cc.x, cc.y); }
    BLOCK(5, WI(0,0,0), WI(0,0,1))
    BLOCK(3, WI(0,2,0), WI(0,2,1))
    BLOCK(1, WI(0,4,0), WI(0,4,1))
    BLOCK(4, WI(0,1,0), WI(0,1,1))
    BLOCK(2, WI(0,3,0), WI(0,3,1))
    BLOCK(5, WI(1,0,0), WI(1,0,1))
    BLOCK(3, WI(1,2,0), WI(1,2,1))
    BLOCK(4, WI(1,1,0), WI(1,1,1))

    // exchange: write S1 map, read S2 map (e = t[7:2]<<8 | l<<2 | t[1:0])
#pragma unroll
    for (int l = 0; l < 64; ++l) lds[swz((l << 8) | t)] = x[l];
    __syncthreads();
    { const int base = ((t >> 2) << 8) | (t & 3);
#pragma unroll
      for (int l = 0; l < 64; ++l) x[l] = lds[swz(base | (l << 2))]; }

    // ---- S2: qubit w -> local bit 11-w
    { float2 cc;
      cc = csv[6];  ry<5>(x, cc.x, cc.y);
      cc = csv[7];  ry<4>(x, cc.x, cc.y);
      cc = csv[8];  ry<3>(x, cc.x, cc.y);
      cc = csv[9];  ry<2>(x, cc.x, cc.y);
      cc = csv[10]; ry<1>(x, cc.x, cc.y);
      cc = csv[11]; ry<0>(x, cc.x, cc.y); }
    BLOCK(5, WI(0,6,0),  WI(0,6,1))
    BLOCK(3, WI(0,8,0),  WI(0,8,1))
    BLOCK(1, WI(0,10,0), WI(0,10,1))
    BLOCK(4, WI(0,7,0),  WI(0,7,1))
    BLOCK(2, WI(0,9,0),  WI(0,9,1))
    BLOCK(3, WI(1,8,0),  WI(1,8,1))

    // exchange: write S2 map (same per-thread addrs as read -> no barrier needed first),
    // read S3 map (e = t<<6 | l)
#pragma unroll
    for (int l = 0; l < 64; ++l) lds[swz(((t >> 2) << 8) | (l << 2) | (t & 3))] = x[l];
    __syncthreads();
#pragma unroll
    for (int l = 0; l < 64; ++l) x[l] = lds[swz((t << 6) | l)];

    // ---- S3: qubit w -> local bit 13-w
    { float2 cc;
      cc = csv[12]; ry<1>(x, cc.x, cc.y);
      cc = csv[13]; ry<0>(x, cc.x, cc.y); }
    BLOCK(1, WI(0,12,0), WI(0,12,1))
    BLOCK(2, WI(0,11,0), WI(0,11,1))
    BLOCK(3, WI(1,10,0), WI(1,10,1))
    BLOCK(1, WI(1,12,0), WI(1,12,1))
    BLOCK(4, WI(1,9,0),  WI(1,9,1))
    BLOCK(2, WI(1,11,0), WI(1,11,1))

    // exchange: write S3 map, read S4 map (e = t[7:5]<<11 | l<<5 | t[4:0])
#pragma unroll
    for (int l = 0; l < 64; ++l) lds[swz((t << 6) | l)] = x[l];
    __syncthreads();
    { const int base = ((t >> 5) << 11) | (t & 31);
#pragma unroll
      for (int l = 0; l < 64; ++l) x[l] = lds[swz(base | (l << 5))]; }

    // ---- S4: qubit w -> local bit 8-w
    BLOCK(3, WI(0,5,0), WI(0,5,1))
    BLOCK(4, WI(1,4,0), WI(1,4,1))
    BLOCK(2, WI(1,6,0), WI(1,6,1))
    BLOCK(5, WI(1,3,0), WI(1,3,1))
    BLOCK(3, WI(1,5,0), WI(1,5,1))
    BLOCK(1, WI(1,7,0), WI(1,7,1))

    // output: probs[:, -1000:] -> element e = 14336 + 32*l + (t&31), j = e - 15384
    if (t >= 224) {
        float* __restrict__ orow = out + (size_t)b * OUT_N;
        const int tb = t & 31;
#pragma unroll
        for (int l = 32; l < 64; ++l) {
            int j = 32 * l + tb - 1048;
            if (j >= 0) orow[j] = x[l] * x[l] * inv;
        }
    }
}

extern "C" void kernel_launch(void* const* d_in, const int* in_sizes, int n_in,
                              void* d_out, int out_size, void* d_ws, size_t ws_size,
                              hipStream_t stream) {
    const float* in   = (const float*)d_in[0];
    const float* wts  = (const float*)d_in[1];
    const float* bias = (const float*)d_in[2];
    float* out = (float*)d_out;
    float2* cs = (float2*)d_ws;

    const int nb = in_sizes[0] / DIM;   // 512 batch rows

    cs_kernel<<<1, 128, 0, stream>>>(wts, bias, cs);
    qnn_kernel<<<nb, 256, 0, stream>>>(in, (const float2*)cs, out);
}

// Round 2
// 92.057 us; speedup vs baseline: 1.2100x; 1.2100x over previous
//
#include <hip/hip_runtime.h>

#define NQ 14
#define DIM 16384
#define OUT_N 1000
#define PRUNED 2048   // amps kept per row after S1 (e bits 13..11 == 111)

using v2f = __attribute__((ext_vector_type(2))) float;

__host__ __device__ constexpr int WI(int l, int i, int k) {
    return 14 + (l * 13 + i) * 2 + k;  // weights[l,i,k] slot after 14 bias slots
}

// Precompute cos(th/2), sin(th/2) for the 66 gate angles into ws.
__global__ void cs_kernel(const float* __restrict__ w,
                          const float* __restrict__ b,
                          float2* __restrict__ cs) {
    int g = threadIdx.x;
    if (g < 66) {
        float th = (g < NQ) ? b[g] : w[g - NQ];
        cs[g] = make_float2(cosf(0.5f * th), sinf(0.5f * th));
    }
}

// LDS xor-swizzle: all exchange patterns become <=2-way bank aliased (free).
__device__ __forceinline__ int swz(int a) { return a ^ ((a >> 5) & 31); }

// RY on element-bit B of a tile of NP float2 pairs (2*NP elements).
// B>=1 uses packed fp32 (v_pk_fma_f32); B==0 is intra-pair scalar.
template<int B, int NP>
__device__ __forceinline__ void ry(v2f* x, float c, float s) {
    if constexpr (B == 0) {
#pragma unroll
        for (int p = 0; p < NP; ++p) {
            float a0 = x[p].x, a1 = x[p].y;
            x[p].x = c * a0 - s * a1;
            x[p].y = s * a0 + c * a1;
        }
    } else {
        constexpr int pb = B - 1;
#pragma unroll
        for (int m = 0; m < NP / 2; ++m) {
            int p0 = ((m >> pb) << (pb + 1)) | (m & ((1 << pb) - 1));
            int p1 = p0 | (1 << pb);
            v2f lo = x[p0], hi = x[p1];
            x[p0] = lo * c - hi * s;
            x[p1] = hi * c + lo * s;
        }
    }
}

// CZ: negate elements with element-bits BH and BL both set.
template<int BH, int BL, int NP>
__device__ __forceinline__ void cz(v2f* x) {
    static_assert(BH > BL, "");
    if constexpr (BL >= 1) {
#pragma unroll
        for (int p = 0; p < NP; ++p)
            if (((p >> (BH - 1)) & 1) && ((p >> (BL - 1)) & 1)) x[p] = -x[p];
    } else {
#pragma unroll
        for (int p = 0; p < NP; ++p)
            if ((p >> (BH - 1)) & 1) x[p].y = -x[p].y;
    }
}

// One entangling block: CZ(BH,BH-1) then RY(I0) on bit BH, RY(I1) on bit BH-1.
#define BLK(BH, I0, I1, NP)                                       \
    cz<BH, BH - 1, NP>(x);                                        \
    { float2 cc = csv[I0]; ry<BH, NP>(x, cc.x, cc.y); }           \
    { float2 cd = csv[I1]; ry<BH - 1, NP>(x, cd.x, cd.y); }

// ---------------- Kernel A: S1 window (qubits 0-5 = e bits 13..8) + prune ----
// layout: e = l<<8 | t ; qubit w -> element-bit 5-w of l.
// S1 gates: init q0-5; B(0,0) B(0,2) B(0,4) B(0,1) B(0,3) B(1,0) B(1,2) B(1,1)
// After S1 no gate touches q0,q1,q2 -> keep only e bits13..11=111 (l in [56,64)).
__global__ __launch_bounds__(256, 2)
void qnnA(const float* __restrict__ in, const float2* __restrict__ csv,
          float* __restrict__ ws) {
    __shared__ float red[4];
    const int t = threadIdx.x;
    const int b = blockIdx.x;
    const float* __restrict__ xin = in + (size_t)b * DIM;

    v2f x[32];
#pragma unroll
    for (int p = 0; p < 32; ++p) {
        x[p].x = xin[((2 * p) << 8) | t];
        x[p].y = xin[((2 * p + 1) << 8) | t];
    }

    // sum of squares -> scale = 1/sqrt(sum); fold normalization into amplitudes
    float pp = 0.f;
#pragma unroll
    for (int p = 0; p < 32; ++p) pp = fmaf(x[p].x, x[p].x, fmaf(x[p].y, x[p].y, pp));
#pragma unroll
    for (int d = 32; d; d >>= 1) pp += __shfl_xor(pp, d);
    if ((t & 63) == 0) red[t >> 6] = pp;
    __syncthreads();
    const float scale = 1.0f / sqrtf(red[0] + red[1] + red[2] + red[3]);

    // init RY layer on q0..q5 (bits 5..0)
    { float2 cc;
      cc = csv[0]; ry<5, 32>(x, cc.x, cc.y);
      cc = csv[1]; ry<4, 32>(x, cc.x, cc.y);
      cc = csv[2]; ry<3, 32>(x, cc.x, cc.y);
      cc = csv[3]; ry<2, 32>(x, cc.x, cc.y);
      cc = csv[4]; ry<1, 32>(x, cc.x, cc.y);
      cc = csv[5]; ry<0, 32>(x, cc.x, cc.y); }
    BLK(5, WI(0,0,0), WI(0,0,1), 32)   // B(0,0): q0,q1
    BLK(3, WI(0,2,0), WI(0,2,1), 32)   // B(0,2): q2,q3
    BLK(1, WI(0,4,0), WI(0,4,1), 32)   // B(0,4): q4,q5
    BLK(4, WI(0,1,0), WI(0,1,1), 32)   // B(0,1): q1,q2
    BLK(2, WI(0,3,0), WI(0,3,1), 32)   // B(0,3): q3,q4
    BLK(5, WI(1,0,0), WI(1,0,1), 32)   // B(1,0)
    BLK(3, WI(1,2,0), WI(1,2,1), 32)   // B(1,2)
    BLK(4, WI(1,1,0), WI(1,1,1), 32)   // B(1,1)

    // prune: keep l in [56,64) -> a = (l-56)<<8 | t, scaled; coalesced store
    float* __restrict__ wrow = ws + (size_t)b * PRUNED;
#pragma unroll
    for (int p = 28; p < 32; ++p) {
        wrow[((2 * p - 56) << 8) | t] = x[p].x * scale;
        wrow[((2 * p - 55) << 8) | t] = x[p].y * scale;
    }
}

// ---------------- Kernel B: remaining gates on 2048-amp pruned rows ----------
// a = e & 2047 ; qubit w -> a bit 13-w (q3->10 ... q13->0). 64 thr, 32 amps/thr.
// Layouts (s=thread, l=reg element):
//  L1: a = s<<5 | l            (reg bits = a4..0 : q9..q13)
//  L2: a = (s>>4)<<9 | l<<4 | (s&15)   (reg bits = a8..4 : q5..q9)
//  L3: a = (s>>2)<<7 | l<<2 | (s&3)    (reg bits = a6..2 : q7..q11)
//  L4: a = l<<6 | s            (reg bits = a10..6 : q3..q7)
// Window schedule (per-qubit order chains verified):
//  U1(L1): init q9-13; B(0,10) B(0,12) B(0,11) B(1,12)
//  U2(L2): init q6-8;  B(0,6) B(0,8) B(0,5) B(0,7) B(1,6)
//  U3(L3): B(0,9) B(1,8) B(1,10) B(1,7) B(1,9)
//  U4(L4): B(1,4) B(1,3) B(1,5)
//  U5(L1): B(1,11)
__global__ __launch_bounds__(64, 4)
void qnnB(const float* __restrict__ ws, const float2* __restrict__ csv,
          float* __restrict__ out) {
    __shared__ float lds[PRUNED];
    const int s = threadIdx.x;
    const int r = blockIdx.x;

    v2f x[16];
    { const float4* __restrict__ src4 =
          (const float4*)(ws + (size_t)r * PRUNED + s * 32);
#pragma unroll
      for (int i = 0; i < 8; ++i) {
          float4 f = src4[i];
          x[2 * i].x = f.x; x[2 * i].y = f.y;
          x[2 * i + 1].x = f.z; x[2 * i + 1].y = f.w;
      } }

    // ---- U1 (L1): q9->4 q10->3 q11->2 q12->1 q13->0
    { float2 cc;
      cc = csv[9];  ry<4, 16>(x, cc.x, cc.y);
      cc = csv[10]; ry<3, 16>(x, cc.x, cc.y);
      cc = csv[11]; ry<2, 16>(x, cc.x, cc.y);
      cc = csv[12]; ry<1, 16>(x, cc.x, cc.y);
      cc = csv[13]; ry<0, 16>(x, cc.x, cc.y); }
    BLK(3, WI(0,10,0), WI(0,10,1), 16)   // B(0,10): q10,q11
    BLK(1, WI(0,12,0), WI(0,12,1), 16)   // B(0,12): q12,q13
    BLK(2, WI(0,11,0), WI(0,11,1), 16)   // B(0,11): q11,q12
    BLK(1, WI(1,12,0), WI(1,12,1), 16)   // B(1,12): q12,q13

    // X1: write L1, read L2
#pragma unroll
    for (int l = 0; l < 32; ++l)
        lds[swz((s << 5) | l)] = (l & 1) ? x[l >> 1].y : x[l >> 1].x;
    __syncthreads();
#pragma unroll
    for (int l = 0; l < 32; ++l) {
        float v = lds[swz(((s >> 4) << 9) | (l << 4) | (s & 15))];
        if (l & 1) x[l >> 1].y = v; else x[l >> 1].x = v;
    }

    // ---- U2 (L2): q5->4 q6->3 q7->2 q8->1 q9->0
    { float2 cc;
      cc = csv[6]; ry<3, 16>(x, cc.x, cc.y);
      cc = csv[7]; ry<2, 16>(x, cc.x, cc.y);
      cc = csv[8]; ry<1, 16>(x, cc.x, cc.y); }
    BLK(3, WI(0,6,0), WI(0,6,1), 16)   // B(0,6): q6,q7
    BLK(1, WI(0,8,0), WI(0,8,1), 16)   // B(0,8): q8,q9
    BLK(4, WI(0,5,0), WI(0,5,1), 16)   // B(0,5): q5,q6
    BLK(2, WI(0,7,0), WI(0,7,1), 16)   // B(0,7): q7,q8
    BLK(3, WI(1,6,0), WI(1,6,1), 16)   // B(1,6): q6,q7

    // X2: write L2 (self-owned addrs), read L3
#pragma unroll
    for (int l = 0; l < 32; ++l)
        lds[swz(((s >> 4) << 9) | (l << 4) | (s & 15))] =
            (l & 1) ? x[l >> 1].y : x[l >> 1].x;
    __syncthreads();
#pragma unroll
    for (int l = 0; l < 32; ++l) {
        float v = lds[swz(((s >> 2) << 7) | (l << 2) | (s & 3))];
        if (l & 1) x[l >> 1].y = v; else x[l >> 1].x = v;
    }

    // ---- U3 (L3): q7->4 q8->3 q9->2 q10->1 q11->0
    BLK(2, WI(0,9,0),  WI(0,9,1),  16)   // B(0,9):  q9,q10
    BLK(3, WI(1,8,0),  WI(1,8,1),  16)   // B(1,8):  q8,q9
    BLK(1, WI(1,10,0), WI(1,10,1), 16)   // B(1,10): q10,q11
    BLK(4, WI(1,7,0),  WI(1,7,1),  16)   // B(1,7):  q7,q8
    BLK(2, WI(1,9,0),  WI(1,9,1),  16)   // B(1,9):  q9,q10

    // X3: write L3, read L4
#pragma unroll
    for (int l = 0; l < 32; ++l)
        lds[swz(((s >> 2) << 7) | (l << 2) | (s & 3))] =
            (l & 1) ? x[l >> 1].y : x[l >> 1].x;
    __syncthreads();
#pragma unroll
    for (int l = 0; l < 32; ++l) {
        float v = lds[swz((l << 6) | s)];
        if (l & 1) x[l >> 1].y = v; else x[l >> 1].x = v;
    }

    // ---- U4 (L4): q3->4 q4->3 q5->2 q6->1 q7->0
    BLK(3, WI(1,4,0), WI(1,4,1), 16)   // B(1,4): q4,q5
    BLK(4, WI(1,3,0), WI(1,3,1), 16)   // B(1,3): q3,q4
    BLK(2, WI(1,5,0), WI(1,5,1), 16)   // B(1,5): q5,q6

    // X4: write L4, read L1
#pragma unroll
    for (int l = 0; l < 32; ++l)
        lds[swz((l << 6) | s)] = (l & 1) ? x[l >> 1].y : x[l >> 1].x;
    __syncthreads();
#pragma unroll
    for (int l = 0; l < 32; ++l) {
        float v = lds[swz((s << 5) | l)];
        if (l & 1) x[l >> 1].y = v; else x[l >> 1].x = v;
    }

    // ---- U5 (L1): B(1,11): q11->2, q12->1
    BLK(2, WI(1,11,0), WI(1,11,1), 16)

    // output: e = 14336 + a, j = a - 1048 for a in [1048,2048)
    if (s >= 32) {
        float* __restrict__ orow = out + (size_t)r * OUT_N;
        const int base = s * 32 - 1048;
#pragma unroll
        for (int l = 0; l < 32; ++l) {
            int j = base + l;
            float v = (l & 1) ? x[l >> 1].y : x[l >> 1].x;
            if (j >= 0) orow[j] = v * v;
        }
    }
}

extern "C" void kernel_launch(void* const* d_in, const int* in_sizes, int n_in,
                              void* d_out, int out_size, void* d_ws, size_t ws_size,
                              hipStream_t stream) {
    const float* in   = (const float*)d_in[0];
    const float* wts  = (const float*)d_in[1];
    const float* bias = (const float*)d_in[2];
    float* out = (float*)d_out;

    float2* cs  = (float2*)d_ws;                 // 66 float2 = 528 B
    float*  buf = (float*)d_ws + 1024;           // pruned amps, 4 MB, 4 KB-aligned

    const int nb = in_sizes[0] / DIM;            // 512 batch rows

    cs_kernel<<<1, 128, 0, stream>>>(wts, bias, cs);
    qnnA<<<nb, 256, 0, stream>>>(in, (const float2*)cs, buf);
    qnnB<<<nb, 64, 0, stream>>>(buf, (const float2*)cs, out);
}